// Round 8
// baseline (84.971 us; speedup 1.0000x reference)
//
#include <hip/hip_runtime.h>
#include <stdint.h>

#define NUM_ACT 6
#define NUM_OPP 3
#define NUM_SAMPLE 80
#define BATCH 4096
#define DIM 512
#define ENT_IDX 98304      /* BATCH*6 + 3*BATCH*6 */

// ---------------- JAX threefry2x32 (key = (0, 42)) ----------------
__device__ __forceinline__ uint32_t rotl32(uint32_t x, int d) {
  return (x << d) | (x >> (32 - d));
}

__device__ __forceinline__ void tf_round4(uint32_t& x0, uint32_t& x1,
                                          int r0, int r1, int r2, int r3) {
  x0 += x1; x1 = rotl32(x1, r0); x1 ^= x0;
  x0 += x1; x1 = rotl32(x1, r1); x1 ^= x0;
  x0 += x1; x1 = rotl32(x1, r2); x1 ^= x0;
  x0 += x1; x1 = rotl32(x1, r3); x1 ^= x0;
}

__device__ __forceinline__ void threefry2x32(uint32_t k0, uint32_t k1,
                                             uint32_t& x0, uint32_t& x1) {
  const uint32_t ks2 = k0 ^ k1 ^ 0x1BD11BDAu;
  x0 += k0;  x1 += k1;
  tf_round4(x0, x1, 13, 15, 26, 6);  x0 += k1;  x1 += ks2 + 1u;
  tf_round4(x0, x1, 17, 29, 16, 24); x0 += ks2; x1 += k0  + 2u;
  tf_round4(x0, x1, 13, 15, 26, 6);  x0 += k0;  x1 += k1  + 3u;
  tf_round4(x0, x1, 17, 29, 16, 24); x0 += k1;  x1 += ks2 + 4u;
  tf_round4(x0, x1, 13, 15, 26, 6);  x0 += ks2; x1 += k0  + 5u;
}

__device__ __forceinline__ float jax_uniform(uint32_t flat_idx) {
  uint32_t x0 = 0u, x1 = flat_idx;
  threefry2x32(0u, 42u, x0, x1);
  uint32_t bits = x0 ^ x1;
  return __uint_as_float((bits >> 9) | 0x3f800000u) - 1.0f;   // [0,1)
}

__device__ __forceinline__ void dot4(float& a, float4 u, float4 v) {
  a = fmaf(u.x, v.x, a); a = fmaf(u.y, v.y, a);
  a = fmaf(u.z, v.z, a); a = fmaf(u.w, v.w, a);
}

// async global->LDS, 16 B per lane; LDS dest is wave-uniform base + lane*16
__device__ __forceinline__ void gload_lds16(const void* g, void* l) {
  __builtin_amdgcn_global_load_lds(
      (const __attribute__((address_space(1))) uint32_t*)g,
      (__attribute__((address_space(3))) uint32_t*)l, 16, 0, 0);
}

// ---------------- LDS layout (floats), total 18996 -> ~74 KB (2 blocks/CU) --
// XS  [8 rows][512] @ 0     : x tile, XOR-swizzled (byte ^= (row&7)<<4)
// WT  [8][24][68]  @ 4096   : weights [chunk][col][dd] (68 = 64+4 pad)
// PART[8][8][24]   @ 17152  : per-chunk partials
// W2  [108]        @ 18688  : tail weights
// DIST[8][18]      @ 18796  : per-wave dist
// XW  [8][6]       @ 18940  : per-wave xw+bias
// HW  [8]          @ 18988  : per-wave entropy
#define O_XS   0
#define O_WT   4096
#define O_PART 17152
#define O_W2   18688
#define O_DIST 18796
#define O_XW   18940
#define O_HW   18988

// ---------------- Single kernel: 8 rows/block, 512 thr, 2 blocks/CU ---------
// All fp sequences bit-identical to verified R6: same per-(row,col,chunk)
// serial dot4 chains, same bias-first g=0..7 column sums, same softmax /
// threefry / CDF / tail. Changes: x staged via global_load_lds with XOR
// swizzle (no ds_writes, no VGPR round-trip); Phase B = 2 rows x 3 cols per
// thread (320 vs 512 ds_read_b128/block, 2-way-free bank aliasing).
__global__ __launch_bounds__(512) void k_all(
    const float* __restrict__ x, const float* __restrict__ Wopp,
    const float* __restrict__ bopp, const float* __restrict__ W,
    const float* __restrict__ bias, float* __restrict__ out) {
  __shared__ float sm[18996];
  const int t = threadIdx.x;
  const int w = t >> 6;            // wave id (phase C: wave = row)
  const int l = t & 63;
  const int rowbase = blockIdx.x * 8;
  const int b = rowbase + w;

  // ---- Phase A: x tile via global_load_lds, source pre-swizzled ----
  // stored byte s in [0,16384): intended byte e = s ^ (((s>>11)&7)<<4)
  // (involution; row bits 11..13 unaffected). LDS linear, global per-lane.
#pragma unroll
  for (int q = 0; q < 2; q++) {
    const uint32_t s = (uint32_t)(w * 2 + q) * 1024u + (uint32_t)l * 16u;
    const uint32_t e = s ^ (((s >> 11) & 7u) << 4);
    const char* gp = (const char*)x + (size_t)(rowbase + (e >> 11)) * 2048 + (e & 2047u);
    gload_lds16(gp, sm + O_XS + (w * 2 + q) * 256);
  }
  // ---- weights: coalesced float4 linear load + LDS transpose-scatter ----
  for (int j = t; j < 3072; j += 512) {                // 6 iters/thread
    int f = j << 2;
    float4 v = (f < 9216) ? *(const float4*)(Wopp + f)
                          : *(const float4*)(W + (f - 9216));
    float vv[4] = {v.x, v.y, v.z, v.w};
#pragma unroll
    for (int e = 0; e < 4; e++) {
      int ff = f + e;
      int c, d;
      if (ff < 9216) { int k = ff / 3072, r = ff % 3072; d = r / 6; c = k * 6 + r % 6; }
      else           { int r = ff - 9216; d = r / 6; c = 18 + r % 6; }
      sm[O_WT + (d >> 6) * 1632 + c * 68 + (d & 63)] = vv[e];
    }
  }
  if (t < 54) {
    float2 v = *(const float2*)(W + DIM * NUM_ACT + 2 * t);
    sm[O_W2 + 2 * t] = v.x; sm[O_W2 + 2 * t + 1] = v.y;
  }
  __syncthreads();   // drains vmcnt (global_load_lds) + lgkm

  // ---- Phase B: GEMM. 256 threads: (chunk sub, row-pair p, col-triple) ----
  if (t < 256) {
    const int sub = t >> 5;            // 0..7 ; wave covers 2 subs (2-way free)
    const int p   = (t >> 3) & 3;      // row-pair 0..3
    const int colg = t & 7;
    const int r0 = p * 2;
    const float* wp = sm + O_WT + sub * 1632 + (colg * 3) * 68;
    const int xb0 = (r0    ) * 512 + sub * 64;   // float idx pre-XOR
    const int xb1 = (r0 + 1) * 512 + sub * 64;
    const int xr0 = ((r0    ) & 7) << 2;         // XOR in float units
    const int xr1 = ((r0 + 1) & 7) << 2;
    float a00 = 0.f, a01 = 0.f, a02 = 0.f;
    float a10 = 0.f, a11 = 0.f, a12 = 0.f;
#pragma unroll 4
    for (int dd = 0; dd < 64; dd += 4) {
      float4 x0 = *(const float4*)(sm + O_XS + ((xb0 + dd) ^ xr0));
      float4 x1 = *(const float4*)(sm + O_XS + ((xb1 + dd) ^ xr1));
      float4 w0 = *(const float4*)(wp + dd);
      float4 w1 = *(const float4*)(wp + 68 + dd);
      float4 w2 = *(const float4*)(wp + 136 + dd);
      dot4(a00, x0, w0); dot4(a01, x0, w1); dot4(a02, x0, w2);
      dot4(a10, x1, w0); dot4(a11, x1, w1); dot4(a12, x1, w2);
    }
    float* pp = sm + O_PART + sub * 192 + r0 * 24 + colg * 3;
    pp[0]  = a00; pp[1]  = a01; pp[2]  = a02;
    pp[24] = a10; pp[25] = a11; pp[26] = a12;
  }
  __syncthreads();

  // ---- Phase C (verified tail; partials from LDS) ----
  // column sums: lane c<24 owns one logit column; bias first, g=0..7.
  float colsum = 0.f;
  if (l < 24) {
    float s = (l < 18) ? bopp[l] : bias[l - 18];
#pragma unroll
    for (int g = 0; g < 8; g++)
      s += sm[O_PART + g * 192 + w * 24 + l];
    colsum = s;
    if (l >= 18) sm[O_XW + w * 6 + (l - 18)] = s;
  }
  // uniform gather (all 64 lanes execute -> no divergent-shuffle UB)
  const int kk = (l < NUM_OPP) ? l : 0;
  float lg[NUM_ACT];
#pragma unroll
  for (int a = 0; a < NUM_ACT; a++)
    lg[a] = __shfl(colsum, kk * NUM_ACT + a);

  // softmax per opponent on lanes 0..2 (identical fp sequence)
  float H = 0.f;
  if (l < NUM_OPP) {
    const int k = l;
    float m = lg[0];
#pragma unroll
    for (int a = 1; a < NUM_ACT; a++) m = fmaxf(m, lg[a]);
    float e[NUM_ACT], Z = 0.f;
#pragma unroll
    for (int a = 0; a < NUM_ACT; a++) { e[a] = expf(lg[a] - m); Z += e[a]; }
    float logZ = logf(Z);
#pragma unroll
    for (int a = 0; a < NUM_ACT; a++) {
      float pa = e[a] / Z;
      sm[O_DIST + w * 18 + k * NUM_ACT + a] = pa;
      H -= pa * ((lg[a] - m) - logZ);
    }
  }
  // gather H0+H1+H2 -> lane 0 (identical shfl sequence)
  H += __shfl_down(H, 1);
  H += __shfl_down(H, 2);
  if (l == 0) sm[O_HW + w] = H;

  // barrier for HW only (no outstanding global stores -> cheap drain)
  __syncthreads();
  if (t == 0) {
    float hs = 0.f;
#pragma unroll
    for (int i = 0; i < 8; i++) hs += sm[O_HW + i];
    atomicAdd(out + ENT_IDX, hs * (1.0f / 12288.0f));  // 512 total, one addr
  }

  // broadcast dist into registers (in-wave DS ordering; no barrier needed)
  float d[18];
#pragma unroll
  for (int i = 0; i < 18; i++) d[i] = sm[O_DIST + w * 18 + i];

  // sampling: a-half (s = l) for k=0,1,2 on every lane
  int   act_a[3];
  float pr_a[3];
#pragma unroll
  for (int k = 0; k < NUM_OPP; k++) {
    float u = jax_uniform((uint32_t)(k * NUM_SAMPLE + l) * BATCH + (uint32_t)b);
    float c = d[k * 6 + 0], pr = d[k * 6 + 0];
    int sel = 0;
#pragma unroll
    for (int a = 1; a < NUM_ACT; a++) {
      bool take = (u >= c);
      sel += take ? 1 : 0;
      pr = take ? d[k * 6 + a] : pr;
      c += d[k * 6 + a];
    }
    act_a[k] = sel; pr_a[k] = pr;
  }
  // b-half (s = 64 + l%16) computed on lanes 0..47, k = l/16
  float prb = 0.f; int actb = 0;
  if (l < 48) {
    const int k = l >> 4, s = 64 + (l & 15);
    float u = jax_uniform((uint32_t)(k * NUM_SAMPLE + s) * BATCH + (uint32_t)b);
    float c = sm[O_DIST + w * 18 + k * 6 + 0], pr = c;
    int sel = 0;
#pragma unroll
    for (int a = 1; a < NUM_ACT; a++) {
      float da = sm[O_DIST + w * 18 + k * 6 + a];
      bool take = (u >= c);
      sel += take ? 1 : 0;
      pr = take ? da : pr;
      c += da;
    }
    actb = sel; prb = pr;
  }
  // redistribute b-half to lanes 0..15 (same sample->lane map: j = t+64)
  const int tm = l & 15;
  float pb0 = __shfl(prb, tm), pb1 = __shfl(prb, tm + 16), pb2 = __shfl(prb, tm + 32);
  int   ab0 = __shfl(actb, tm), ab1 = __shfl(actb, tm + 16), ab2 = __shfl(actb, tm + 32);

  const bool hasb = l < (NUM_SAMPLE - 64);
  float p1a = pr_a[0] * pr_a[1] * pr_a[2];
  float p1b = 0.f;
  if (hasb) p1b = pb0 * pb1 * pb2;
  float tot = p1a + p1b;
#pragma unroll
  for (int m = 32; m > 0; m >>= 1) tot += __shfl_xor(tot, m);

  float xw[NUM_ACT];
#pragma unroll
  for (int a = 0; a < NUM_ACT; a++) xw[a] = sm[O_XW + w * 6 + a];

  float o[NUM_ACT];
#pragma unroll
  for (int a = 0; a < NUM_ACT; a++) o[a] = 0.f;
  {
    int a0 = act_a[0], a1 = act_a[1], a2 = act_a[2];
    float la[NUM_ACT];
#pragma unroll
    for (int a = 0; a < NUM_ACT; a++)
      la[a] = xw[a] + sm[O_W2 + a0 * 6 + a] + sm[O_W2 + (6 + a1) * 6 + a]
                    + sm[O_W2 + (12 + a2) * 6 + a];
    float m = la[0];
#pragma unroll
    for (int a = 1; a < NUM_ACT; a++) m = fmaxf(m, la[a]);
    float e[NUM_ACT], Z = 0.f;
#pragma unroll
    for (int a = 0; a < NUM_ACT; a++) { e[a] = expf(la[a] - m); Z += e[a]; }
    float wz = (p1a / tot) / Z;
#pragma unroll
    for (int a = 0; a < NUM_ACT; a++) o[a] = wz * e[a];
  }
  if (hasb) {
    float la[NUM_ACT];
#pragma unroll
    for (int a = 0; a < NUM_ACT; a++)
      la[a] = xw[a] + sm[O_W2 + ab0 * 6 + a] + sm[O_W2 + (6 + ab1) * 6 + a]
                    + sm[O_W2 + (12 + ab2) * 6 + a];
    float m = la[0];
#pragma unroll
    for (int a = 1; a < NUM_ACT; a++) m = fmaxf(m, la[a]);
    float e[NUM_ACT], Z = 0.f;
#pragma unroll
    for (int a = 0; a < NUM_ACT; a++) { e[a] = expf(la[a] - m); Z += e[a]; }
    float wz = (p1b / tot) / Z;
#pragma unroll
    for (int a = 0; a < NUM_ACT; a++) o[a] += wz * e[a];
  }
#pragma unroll
  for (int m = 32; m > 0; m >>= 1)
#pragma unroll
    for (int a = 0; a < NUM_ACT; a++) o[a] += __shfl_xor(o[a], m);

  // fire-and-forget outputs (no barrier after any of these)
  if (l == 0) {
#pragma unroll
    for (int a = 0; a < NUM_ACT; a++) out[b * NUM_ACT + a] = o[a];
  }
  if (l < 18) {
    int k = l / 6, a = l - k * 6;
    out[BATCH * NUM_ACT + ((size_t)k * BATCH + b) * NUM_ACT + a] =
        sm[O_DIST + w * 18 + l];
  }
}

extern "C" void kernel_launch(void* const* d_in, const int* in_sizes, int n_in,
                              void* d_out, int out_size, void* d_ws, size_t ws_size,
                              hipStream_t stream) {
  const float* x    = (const float*)d_in[0];
  const float* Wopp = (const float*)d_in[1];
  const float* bopp = (const float*)d_in[2];
  const float* W    = (const float*)d_in[3];
  const float* bias = (const float*)d_in[4];
  float* out = (float*)d_out;

  // zero the 4-byte entropy accumulator (stream-ordered, graph-capturable; R1)
  hipMemsetAsync(out + ENT_IDX, 0, sizeof(float), stream);
  k_all<<<BATCH / 8, 512, 0, stream>>>(x, Wopp, bopp, W, bias, out);
}

// Round 9
// 81.875 us; speedup vs baseline: 1.0378x; 1.0378x over previous
//
#include <hip/hip_runtime.h>
#include <stdint.h>

#define NUM_ACT 6
#define NUM_OPP 3
#define NUM_SAMPLE 80
#define BATCH 4096
#define DIM 512
#define ENT_IDX 98304      /* BATCH*6 + 3*BATCH*6 */

// ---------------- JAX threefry2x32 (key = (0, 42)) ----------------
__device__ __forceinline__ uint32_t rotl32(uint32_t x, int d) {
  return (x << d) | (x >> (32 - d));
}

__device__ __forceinline__ void tf_round4(uint32_t& x0, uint32_t& x1,
                                          int r0, int r1, int r2, int r3) {
  x0 += x1; x1 = rotl32(x1, r0); x1 ^= x0;
  x0 += x1; x1 = rotl32(x1, r1); x1 ^= x0;
  x0 += x1; x1 = rotl32(x1, r2); x1 ^= x0;
  x0 += x1; x1 = rotl32(x1, r3); x1 ^= x0;
}

__device__ __forceinline__ void threefry2x32(uint32_t k0, uint32_t k1,
                                             uint32_t& x0, uint32_t& x1) {
  const uint32_t ks2 = k0 ^ k1 ^ 0x1BD11BDAu;
  x0 += k0;  x1 += k1;
  tf_round4(x0, x1, 13, 15, 26, 6);  x0 += k1;  x1 += ks2 + 1u;
  tf_round4(x0, x1, 17, 29, 16, 24); x0 += ks2; x1 += k0  + 2u;
  tf_round4(x0, x1, 13, 15, 26, 6);  x0 += k0;  x1 += k1  + 3u;
  tf_round4(x0, x1, 17, 29, 16, 24); x0 += k1;  x1 += ks2 + 4u;
  tf_round4(x0, x1, 13, 15, 26, 6);  x0 += ks2; x1 += k0  + 5u;
}

__device__ __forceinline__ float jax_uniform(uint32_t flat_idx) {
  uint32_t x0 = 0u, x1 = flat_idx;
  threefry2x32(0u, 42u, x0, x1);
  uint32_t bits = x0 ^ x1;
  return __uint_as_float((bits >> 9) | 0x3f800000u) - 1.0f;   // [0,1)
}

__device__ __forceinline__ void dot4(float& a, float4 u, float4 v) {
  a = fmaf(u.x, v.x, a); a = fmaf(u.y, v.y, a);
  a = fmaf(u.z, v.z, a); a = fmaf(u.w, v.w, a);
}

// ---------------- LDS layout (floats), total 19252 -> ~75 KB (2 blocks/CU) --
// XS  [8][8][68]   @ 0      : x tile  [chunk][row][dd] (68 = 64+4 pad)
// WT  [8][24][68]  @ 4352   : weights [chunk][col][dd]
// PART[8][8][24]   @ 17408  : per-chunk partials
// W2  [108]        @ 18944  : tail weights
// DIST[8][18]      @ 19052  : per-wave dist
// XW  [8][6]       @ 19196  : per-wave xw+bias
// HW  [8]          @ 19244  : per-wave entropy
#define O_XS   0
#define O_WT   4352
#define O_PART 17408
#define O_W2   18944
#define O_DIST 19052
#define O_XW   19196
#define O_HW   19244

// ---------------- Single kernel: 8 rows/block, 512 thr, 2 blocks/CU ---------
// Measured-best configuration (R6, 81.4 us). R8's gload_lds + half-width
// Phase B regressed to 85.0 us -> reverted. All fp sequences bit-identical
// to the verified chain: per-(row,col,chunk) serial dot4 chains, bias-first
// g=0..7 column sums, identical softmax / threefry / CDF / tail.
__global__ __launch_bounds__(512) void k_all(
    const float* __restrict__ x, const float* __restrict__ Wopp,
    const float* __restrict__ bopp, const float* __restrict__ W,
    const float* __restrict__ bias, float* __restrict__ out) {
  __shared__ float sm[19252];
  const int t = threadIdx.x;
  const int w = t >> 6;            // wave = row within tile (phase C)
  const int l = t & 63;
  const int rowbase = blockIdx.x * 8;
  const int b = rowbase + w;

  // ---- Phase A: stage x tile (coalesced float4) ----
  for (int u = t; u < 8 * 128; u += 512) {             // 1024 float4 = 16 KB
    int row = u >> 7, c4 = (u & 127) << 2;             // d = c4 in [0,512)
    float4 v = *(const float4*)(x + (size_t)(rowbase + row) * DIM + c4);
    *(float4*)(sm + O_XS + (c4 >> 6) * 544 + row * 68 + (c4 & 63)) = v;
  }
  // ---- weights: coalesced float4 linear load + LDS transpose-scatter ----
  for (int j = t; j < 3072; j += 512) {                // 6 iters/thread
    int f = j << 2;
    float4 v = (f < 9216) ? *(const float4*)(Wopp + f)
                          : *(const float4*)(W + (f - 9216));
    float vv[4] = {v.x, v.y, v.z, v.w};
#pragma unroll
    for (int e = 0; e < 4; e++) {
      int ff = f + e;
      int c, d;
      if (ff < 9216) { int k = ff / 3072, r = ff % 3072; d = r / 6; c = k * 6 + r % 6; }
      else           { int r = ff - 9216; d = r / 6; c = 18 + r % 6; }
      sm[O_WT + (d >> 6) * 1632 + c * 68 + (d & 63)] = vv[e];
    }
  }
  if (t < 54) {
    float2 v = *(const float2*)(W + DIM * NUM_ACT + 2 * t);
    sm[O_W2 + 2 * t] = v.x; sm[O_W2 + 2 * t + 1] = v.y;
  }
  __syncthreads();

  // ---- Phase B: GEMM. thread = (chunk sub = wave, row, col-triple) ----
  {
    const int sub = t >> 6, row = (t >> 3) & 7, colg = t & 7;
    const float* xp = sm + O_XS + sub * 544 + row * 68;
    const float* wp = sm + O_WT + sub * 1632 + (colg * 3) * 68;
    float a0 = 0.f, a1 = 0.f, a2 = 0.f;
#pragma unroll 4
    for (int dd = 0; dd < 64; dd += 4) {
      float4 xv = *(const float4*)(xp + dd);
      dot4(a0, xv, *(const float4*)(wp + dd));
      dot4(a1, xv, *(const float4*)(wp + 68 + dd));
      dot4(a2, xv, *(const float4*)(wp + 136 + dd));
    }
    float* pp = sm + O_PART + sub * 192 + row * 24 + colg * 3;
    pp[0] = a0; pp[1] = a1; pp[2] = a2;
  }
  __syncthreads();

  // ---- Phase C (verified tail; partials from LDS) ----
  // column sums: lane c<24 owns one logit column; bias first, g=0..7.
  float colsum = 0.f;
  if (l < 24) {
    float s = (l < 18) ? bopp[l] : bias[l - 18];
#pragma unroll
    for (int g = 0; g < 8; g++)
      s += sm[O_PART + g * 192 + w * 24 + l];
    colsum = s;
    if (l >= 18) sm[O_XW + w * 6 + (l - 18)] = s;
  }
  // uniform gather (all 64 lanes execute -> no divergent-shuffle UB)
  const int kk = (l < NUM_OPP) ? l : 0;
  float lg[NUM_ACT];
#pragma unroll
  for (int a = 0; a < NUM_ACT; a++)
    lg[a] = __shfl(colsum, kk * NUM_ACT + a);

  // softmax per opponent on lanes 0..2 (identical fp sequence)
  float H = 0.f;
  if (l < NUM_OPP) {
    const int k = l;
    float m = lg[0];
#pragma unroll
    for (int a = 1; a < NUM_ACT; a++) m = fmaxf(m, lg[a]);
    float e[NUM_ACT], Z = 0.f;
#pragma unroll
    for (int a = 0; a < NUM_ACT; a++) { e[a] = expf(lg[a] - m); Z += e[a]; }
    float logZ = logf(Z);
#pragma unroll
    for (int a = 0; a < NUM_ACT; a++) {
      float pa = e[a] / Z;
      sm[O_DIST + w * 18 + k * NUM_ACT + a] = pa;
      H -= pa * ((lg[a] - m) - logZ);
    }
  }
  // gather H0+H1+H2 -> lane 0 (identical shfl sequence)
  H += __shfl_down(H, 1);
  H += __shfl_down(H, 2);
  if (l == 0) sm[O_HW + w] = H;

  // barrier for HW only (no outstanding global stores -> cheap drain)
  __syncthreads();
  if (t == 0) {
    float hs = 0.f;
#pragma unroll
    for (int i = 0; i < 8; i++) hs += sm[O_HW + i];
    atomicAdd(out + ENT_IDX, hs * (1.0f / 12288.0f));  // 512 total, one addr
  }

  // broadcast dist into registers (in-wave DS ordering; no barrier needed)
  float d[18];
#pragma unroll
  for (int i = 0; i < 18; i++) d[i] = sm[O_DIST + w * 18 + i];

  // sampling: a-half (s = l) for k=0,1,2 on every lane
  int   act_a[3];
  float pr_a[3];
#pragma unroll
  for (int k = 0; k < NUM_OPP; k++) {
    float u = jax_uniform((uint32_t)(k * NUM_SAMPLE + l) * BATCH + (uint32_t)b);
    float c = d[k * 6 + 0], pr = d[k * 6 + 0];
    int sel = 0;
#pragma unroll
    for (int a = 1; a < NUM_ACT; a++) {
      bool take = (u >= c);
      sel += take ? 1 : 0;
      pr = take ? d[k * 6 + a] : pr;
      c += d[k * 6 + a];
    }
    act_a[k] = sel; pr_a[k] = pr;
  }
  // b-half (s = 64 + l%16) computed on lanes 0..47, k = l/16
  float prb = 0.f; int actb = 0;
  if (l < 48) {
    const int k = l >> 4, s = 64 + (l & 15);
    float u = jax_uniform((uint32_t)(k * NUM_SAMPLE + s) * BATCH + (uint32_t)b);
    float c = sm[O_DIST + w * 18 + k * 6 + 0], pr = c;
    int sel = 0;
#pragma unroll
    for (int a = 1; a < NUM_ACT; a++) {
      float da = sm[O_DIST + w * 18 + k * 6 + a];
      bool take = (u >= c);
      sel += take ? 1 : 0;
      pr = take ? da : pr;
      c += da;
    }
    actb = sel; prb = pr;
  }
  // redistribute b-half to lanes 0..15 (same sample->lane map: j = t+64)
  const int tm = l & 15;
  float pb0 = __shfl(prb, tm), pb1 = __shfl(prb, tm + 16), pb2 = __shfl(prb, tm + 32);
  int   ab0 = __shfl(actb, tm), ab1 = __shfl(actb, tm + 16), ab2 = __shfl(actb, tm + 32);

  const bool hasb = l < (NUM_SAMPLE - 64);
  float p1a = pr_a[0] * pr_a[1] * pr_a[2];
  float p1b = 0.f;
  if (hasb) p1b = pb0 * pb1 * pb2;
  float tot = p1a + p1b;
#pragma unroll
  for (int m = 32; m > 0; m >>= 1) tot += __shfl_xor(tot, m);

  float xw[NUM_ACT];
#pragma unroll
  for (int a = 0; a < NUM_ACT; a++) xw[a] = sm[O_XW + w * 6 + a];

  float o[NUM_ACT];
#pragma unroll
  for (int a = 0; a < NUM_ACT; a++) o[a] = 0.f;
  {
    int a0 = act_a[0], a1 = act_a[1], a2 = act_a[2];
    float la[NUM_ACT];
#pragma unroll
    for (int a = 0; a < NUM_ACT; a++)
      la[a] = xw[a] + sm[O_W2 + a0 * 6 + a] + sm[O_W2 + (6 + a1) * 6 + a]
                    + sm[O_W2 + (12 + a2) * 6 + a];
    float m = la[0];
#pragma unroll
    for (int a = 1; a < NUM_ACT; a++) m = fmaxf(m, la[a]);
    float e[NUM_ACT], Z = 0.f;
#pragma unroll
    for (int a = 0; a < NUM_ACT; a++) { e[a] = expf(la[a] - m); Z += e[a]; }
    float wz = (p1a / tot) / Z;
#pragma unroll
    for (int a = 0; a < NUM_ACT; a++) o[a] = wz * e[a];
  }
  if (hasb) {
    float la[NUM_ACT];
#pragma unroll
    for (int a = 0; a < NUM_ACT; a++)
      la[a] = xw[a] + sm[O_W2 + ab0 * 6 + a] + sm[O_W2 + (6 + ab1) * 6 + a]
                    + sm[O_W2 + (12 + ab2) * 6 + a];
    float m = la[0];
#pragma unroll
    for (int a = 1; a < NUM_ACT; a++) m = fmaxf(m, la[a]);
    float e[NUM_ACT], Z = 0.f;
#pragma unroll
    for (int a = 0; a < NUM_ACT; a++) { e[a] = expf(la[a] - m); Z += e[a]; }
    float wz = (p1b / tot) / Z;
#pragma unroll
    for (int a = 0; a < NUM_ACT; a++) o[a] += wz * e[a];
  }
#pragma unroll
  for (int m = 32; m > 0; m >>= 1)
#pragma unroll
    for (int a = 0; a < NUM_ACT; a++) o[a] += __shfl_xor(o[a], m);

  // fire-and-forget outputs (no barrier after any of these)
  if (l == 0) {
#pragma unroll
    for (int a = 0; a < NUM_ACT; a++) out[b * NUM_ACT + a] = o[a];
  }
  if (l < 18) {
    int k = l / 6, a = l - k * 6;
    out[BATCH * NUM_ACT + ((size_t)k * BATCH + b) * NUM_ACT + a] =
        sm[O_DIST + w * 18 + l];
  }
}

extern "C" void kernel_launch(void* const* d_in, const int* in_sizes, int n_in,
                              void* d_out, int out_size, void* d_ws, size_t ws_size,
                              hipStream_t stream) {
  const float* x    = (const float*)d_in[0];
  const float* Wopp = (const float*)d_in[1];
  const float* bopp = (const float*)d_in[2];
  const float* W    = (const float*)d_in[3];
  const float* bias = (const float*)d_in[4];
  float* out = (float*)d_out;

  // zero the 4-byte entropy accumulator (stream-ordered, graph-capturable; R1)
  hipMemsetAsync(out + ENT_IDX, 0, sizeof(float), stream);
  k_all<<<BATCH / 8, 512, 0, stream>>>(x, Wopp, bopp, W, bias, out);
}